// Round 17
// baseline (326.295 us; speedup 1.0000x reference)
//
#include <hip/hip_runtime.h>
#include <hip/hip_bf16.h>

#define S_LEN 2048
#define HID 4096
#define NH 32
#define NKV 8
#define HD 128

typedef __attribute__((ext_vector_type(4))) float f32x4;
typedef __attribute__((ext_vector_type(8))) __bf16 bf16x8;
typedef __attribute__((ext_vector_type(8))) unsigned short u16x8;
typedef __attribute__((ext_vector_type(4))) unsigned short u16x4;

static __device__ __forceinline__ unsigned short f2bf(float x) {
  return __builtin_bit_cast(unsigned short, __float2bfloat16(x));
}
static __device__ __forceinline__ float bf2f(unsigned short u) {
  return __builtin_bit_cast(float, (unsigned int)u << 16);
}
static __device__ __forceinline__ void gld16(const unsigned short* g, unsigned short* l) {
  __builtin_amdgcn_global_load_lds(
      (const __attribute__((address_space(1))) unsigned int*)g,
      (__attribute__((address_space(3))) unsigned int*)l, 16, 0, 0);
}
static __device__ __forceinline__ void cvt8(const float* src, size_t off8, unsigned short* dst) {
  f32x4 a = ((const f32x4*)src)[off8 * 2];
  f32x4 b = ((const f32x4*)src)[off8 * 2 + 1];
  u16x8 w;
#pragma unroll
  for (int j = 0; j < 4; ++j) {
    w[j] = f2bf(a[j]);
    w[4 + j] = f2bf(b[j]);
  }
  ((u16x8*)dst)[off8] = w;
}

// ---------------- fp32 -> bf16 bulk convert (fallback path for wo) ----------------
__global__ void f2bf_kernel(const float* __restrict__ in, unsigned short* __restrict__ out, int n8) {
  int i = blockIdx.x * 256 + threadIdx.x;
  if (i >= n8) return;
  cvt8(in, (size_t)i, out);
}

// ---------------- prep: hidden + qkv weights + wo + rope table, ONE launch ----------------
__global__ void prep_all(const float* __restrict__ hidden, const float* __restrict__ wq,
                         const float* __restrict__ wk, const float* __restrict__ wv,
                         const float* __restrict__ woSrc,
                         unsigned short* __restrict__ hb, unsigned short* __restrict__ wbuf,
                         unsigned short* __restrict__ woDst, float* __restrict__ cs) {
  int i = blockIdx.x * 256 + threadIdx.x;
  if (i < 1048576) {
    cvt8(hidden, (size_t)i, hb);
  } else if (i < 4194304) {
    int j = i - 1048576;
    const float* src;
    size_t off;
    if (j < 2097152) { src = wq; off = j; }
    else if (j < 2621440) { src = wk; off = j - 2097152; }
    else { src = wv; off = j - 2621440; }
    f32x4 a = ((const f32x4*)src)[off * 2];
    f32x4 b = ((const f32x4*)src)[off * 2 + 1];
    u16x8 w;
#pragma unroll
    for (int jj = 0; jj < 4; ++jj) {
      w[jj] = f2bf(a[jj]);
      w[4 + jj] = f2bf(b[jj]);
    }
    ((u16x8*)wbuf)[(size_t)j] = w;
  } else if (i < 6291456) {
    if (woDst) cvt8(woSrc, (size_t)(i - 4194304), woDst);
  } else {
    int idx = i - 6291456;
    if (idx < S_LEN * 64) {
      int d = idx & 63;
      int p = idx >> 6;
      float invf = exp2f(-(float)d * (19.9315685693241741f / 64.0f));  // theta^-d/64
      float ang = (float)p * invf;
      cs[idx] = cosf(ang);
      cs[S_LEN * 64 + idx] = sinf(ang);
    }
  }
}

// ---------------- RoPE apply, K only (in-place, bf16 [head][S][128]) ----------------
__global__ void rope_apply_k(unsigned short* __restrict__ buf, const float* __restrict__ cs) {
  int idx = blockIdx.x * 256 + threadIdx.x;
  if (idx >= NKV * S_LEN * 64) return;
  int d = idx & 63;
  int hp = idx >> 6;
  int pos = hp & (S_LEN - 1);
  size_t base = (size_t)hp * HD;
  float c = cs[pos * 64 + d];
  float s = cs[S_LEN * 64 + pos * 64 + d];
  float x1 = bf2f(buf[base + d]);
  float x2 = bf2f(buf[base + 64 + d]);
  buf[base + d] = f2bf(x1 * c - x2 * s);
  buf[base + 64 + d] = f2bf(x2 * c + x1 * s);
}

// ---------------- QKV GEMM (EXACT round-2/R11 m97 structure, 852 TF measured) ----------------
// 128x128 tile, BK=32, single LDS buffer, global_load_lds(16B), 2 barriers/K-step.
// Q written WITHOUT rope (attn applies it on load).
template <int MODE>
__global__ __launch_bounds__(256) void gemm_nt(
    const unsigned short* __restrict__ A, const unsigned short* __restrict__ W,
    const float* __restrict__ bq, const float* __restrict__ bk, const float* __restrict__ bv,
    unsigned short* __restrict__ Qb, unsigned short* __restrict__ Kb,
    unsigned short* __restrict__ VTb) {
  __shared__ unsigned short As[4096];  // [128 rows][32] linear
  __shared__ unsigned short Bs[4096];
  int lin = blockIdx.x + 16 * blockIdx.y;
  int cpx = (16 * gridDim.y) >> 3;
  int swz = (lin & 7) * cpx + (lin >> 3);
  const int m0 = (swz & 15) * 128;
  const int n0 = (swz >> 4) * 128;
  const int tid = threadIdx.x, lane = tid & 63, wv = tid >> 6;
  const int wr = wv >> 1, wc = wv & 1;
  const int lr = lane & 15, lg = lane >> 4;
  const int srow = lane >> 2, skk = (lane & 3) * 8;

  const unsigned short* Ag0 = A + (size_t)(m0 + wv * 32 + srow) * HID + skk;
  const unsigned short* Ag1 = Ag0 + (size_t)16 * HID;
  const unsigned short* Wg0 = W + (size_t)(n0 + wv * 32 + srow) * HID + skk;
  const unsigned short* Wg1 = Wg0 + (size_t)16 * HID;
  unsigned short* Al0 = As + wv * 1024;  // wave-uniform LDS slice bases
  unsigned short* Al1 = As + wv * 1024 + 512;
  unsigned short* Bl0 = Bs + wv * 1024;
  unsigned short* Bl1 = Bs + wv * 1024 + 512;

  f32x4 acc[4][4] = {};

  for (int kt = 0; kt < HID / 32; ++kt) {
    const int ko = kt * 32;
    gld16(Ag0 + ko, Al0);
    gld16(Ag1 + ko, Al1);
    gld16(Wg0 + ko, Bl0);
    gld16(Wg1 + ko, Bl1);
    __syncthreads();  // drains vmcnt -> tile visible
    bf16x8 af[4], bfr[4];
#pragma unroll
    for (int i = 0; i < 4; ++i)
      af[i] = *(const bf16x8*)&As[(wr * 64 + i * 16 + lr) * 32 + lg * 8];
#pragma unroll
    for (int i = 0; i < 4; ++i)
      bfr[i] = *(const bf16x8*)&Bs[(wc * 64 + i * 16 + lr) * 32 + lg * 8];
#pragma unroll
    for (int mi = 0; mi < 4; ++mi)
#pragma unroll
      for (int ni = 0; ni < 4; ++ni)
        acc[mi][ni] = __builtin_amdgcn_mfma_f32_16x16x32_bf16(af[mi], bfr[ni], acc[mi][ni], 0, 0, 0);
    __syncthreads();  // reads done -> next stage may overwrite
  }

  {
    unsigned short* obuf;
    const float* bptr;
    int cbase;
    bool transp = false;
    if (n0 < 4096) { obuf = Qb; bptr = bq; cbase = n0; }
    else if (n0 < 5120) { obuf = Kb; bptr = bk; cbase = n0 - 4096; }
    else { obuf = VTb; bptr = bv; cbase = n0 - 5120; transp = true; }
#pragma unroll
    for (int ni = 0; ni < 4; ++ni) {
      int c = cbase + wc * 64 + ni * 16 + lr;
      float bb = bptr[c];
      if (!transp) {
        int head = c >> 7, d = c & 127;
#pragma unroll
        for (int mi = 0; mi < 4; ++mi) {
          int row = m0 + wr * 64 + mi * 16 + lg * 4;
#pragma unroll
          for (int j = 0; j < 4; ++j)
            obuf[((size_t)head * S_LEN + row + j) * HD + d] = f2bf(acc[mi][ni][j] + bb);
        }
      } else {
#pragma unroll
        for (int mi = 0; mi < 4; ++mi) {
          int row = m0 + wr * 64 + mi * 16 + lg * 4;
          u16x4 pk;
#pragma unroll
          for (int j = 0; j < 4; ++j) pk[j] = f2bf(acc[mi][ni][j] + bb);
          *(u16x4*)&VTb[(size_t)c * S_LEN + row] = pk;
        }
      }
    }
  }
}

// ---------------- Out-projection: phase rhythm + T2 swizzle (unchanged from R11-R16) ----------------
__global__ __launch_bounds__(512) void gemm_op8(const unsigned short* __restrict__ A,
                                                const unsigned short* __restrict__ W,
                                                float* __restrict__ Cout) {
  __shared__ __align__(16) unsigned short Asl[3][256 * 64];  // 96 KB
  __shared__ __align__(16) unsigned short Bsl[3][128 * 64];  // 48 KB
  int lin = blockIdx.x + 8 * blockIdx.y;
  int swz = (lin & 7) * 32 + (lin >> 3);  // XCD-chunked
  const int m0 = (swz & 7) * 256;
  const int n0 = (swz >> 3) * 128;
  const int tid = threadIdx.x, lane = tid & 63, wv = tid >> 6;
  const int wr = wv >> 1, wc = wv & 1;  // 4M x 2N waves, per-wave 64x64
  const int lr = lane & 15, lg = lane >> 4;

  const int sslot = (tid & 7) ^ ((tid >> 3) & 7);
  const unsigned short* Ag = A + (size_t)(m0 + (tid >> 3)) * HID + sslot * 8;
  const unsigned short* Wg = W + (size_t)(n0 + (tid >> 3)) * HID + sslot * 8;

  f32x4 acc[4][4] = {};

#define STAGE_A3(buf, kt)                                                     \
  {                                                                           \
    const int ko_ = (kt)*64;                                                  \
    gld16(Ag + ko_, &Asl[buf][wv * 512]);                                     \
    gld16(Ag + ko_ + (size_t)64 * HID, &Asl[buf][4096 + wv * 512]);           \
    gld16(Ag + ko_ + (size_t)128 * HID, &Asl[buf][8192 + wv * 512]);          \
  }
#define STAGE_B3(buf, kt)                                                     \
  {                                                                           \
    const int ko_ = (kt)*64;                                                  \
    gld16(Ag + ko_ + (size_t)192 * HID, &Asl[buf][12288 + wv * 512]);         \
    gld16(Wg + ko_, &Bsl[buf][wv * 512]);                                     \
    gld16(Wg + ko_ + (size_t)64 * HID, &Bsl[buf][4096 + wv * 512]);           \
  }

  STAGE_A3(0, 0); STAGE_B3(0, 0);
  STAGE_A3(1, 1); STAGE_B3(1, 1);
  asm volatile("s_waitcnt vmcnt(6)" ::: "memory");
  __builtin_amdgcn_s_barrier();

  const int NT = HID / 64;  // 64
#pragma unroll 1
  for (int kt = 0; kt < NT; ++kt) {
    const int cur = kt % 3;
    const int nxt = (kt + 2) % 3;
    bf16x8 af[4], bfr[4];
    // ---- phase 0
#pragma unroll
    for (int i = 0; i < 4; ++i)
      af[i] = *(const bf16x8*)&Asl[cur][(wr * 64 + i * 16 + lr) * 64 + ((lg ^ (lr & 7)) * 8)];
#pragma unroll
    for (int i = 0; i < 4; ++i)
      bfr[i] = *(const bf16x8*)&Bsl[cur][(wc * 64 + i * 16 + lr) * 64 + ((lg ^ (lr & 7)) * 8)];
    if (kt + 2 < NT) STAGE_A3(nxt, kt + 2);
    __builtin_amdgcn_s_barrier();
    asm volatile("s_waitcnt lgkmcnt(0)" ::: "memory");
    __builtin_amdgcn_s_setprio(1);
#pragma unroll
    for (int mi = 0; mi < 4; ++mi)
#pragma unroll
      for (int ni = 0; ni < 4; ++ni)
        acc[mi][ni] = __builtin_amdgcn_mfma_f32_16x16x32_bf16(af[mi], bfr[ni], acc[mi][ni], 0, 0, 0);
    __builtin_amdgcn_s_setprio(0);
    __builtin_amdgcn_s_barrier();
    // ---- phase 1
#pragma unroll
    for (int i = 0; i < 4; ++i)
      af[i] = *(const bf16x8*)&Asl[cur][(wr * 64 + i * 16 + lr) * 64 + (((4 + lg) ^ (lr & 7)) * 8)];
#pragma unroll
    for (int i = 0; i < 4; ++i)
      bfr[i] = *(const bf16x8*)&Bsl[cur][(wc * 64 + i * 16 + lr) * 64 + (((4 + lg) ^ (lr & 7)) * 8)];
    if (kt + 2 < NT) {
      STAGE_B3(nxt, kt + 2);
      asm volatile("s_waitcnt vmcnt(6)" ::: "memory");
    } else if (kt + 1 < NT) {
      asm volatile("s_waitcnt vmcnt(0)" ::: "memory");
    }
    __builtin_amdgcn_s_barrier();
    asm volatile("s_waitcnt lgkmcnt(0)" ::: "memory");
    __builtin_amdgcn_s_setprio(1);
#pragma unroll
    for (int mi = 0; mi < 4; ++mi)
#pragma unroll
      for (int ni = 0; ni < 4; ++ni)
        acc[mi][ni] = __builtin_amdgcn_mfma_f32_16x16x32_bf16(af[mi], bfr[ni], acc[mi][ni], 0, 0, 0);
    __builtin_amdgcn_s_setprio(0);
    __builtin_amdgcn_s_barrier();
  }
#undef STAGE_A3
#undef STAGE_B3

#pragma unroll
  for (int mi = 0; mi < 4; ++mi) {
    int row = m0 + wr * 64 + mi * 16 + lg * 4;
#pragma unroll
    for (int ni = 0; ni < 4; ++ni) {
      int col = n0 + wc * 64 + ni * 16 + lr;
#pragma unroll
      for (int j = 0; j < 4; ++j)
        Cout[(size_t)(row + j) * HID + col] = acc[mi][ni][j];
    }
  }
}

// ---------------- Flash attention: QBLK=64, 4 waves, 512 blocks = 2/CU ----------------
// LDS 79 KB < 80 KB -> TWO co-resident blocks per CU with independent barriers:
// when one block stalls at its barrier/lgkm wait, the other block's waves issue.
// Balanced pairs over 32 q-tiles (block p: tiles p and 31-p = 33 KV tiles).
// Same dbuf 1-barrier/tile pipeline as R16; per-wave fragment work identical;
// 16-row wave groups unchanged -> defer-max decisions and accumulation order
// identical -> absmax bitwise unchanged.
__global__ __launch_bounds__(256) void attn_fwd(const unsigned short* __restrict__ Qb,
                                                const unsigned short* __restrict__ Kb,
                                                const unsigned short* __restrict__ VTb,
                                                const float* __restrict__ cs,
                                                unsigned short* __restrict__ Ob) {
  __shared__ unsigned short Kl[2][64][136];
  __shared__ unsigned short Vt[2][128][72];
  __shared__ unsigned short Pl[4][16][72];
  int lin = blockIdx.x + 16 * blockIdx.y;          // [0,512)
  int swz = (lin & 7) * 64 + (lin >> 3);           // each XCD owns 4 q-heads = 1 kv-head
  const int pair = swz & 15;
  const int h = swz >> 4;
  const int kh = h >> 2;
  const int tid = threadIdx.x, lane = tid & 63, wv = tid >> 6;  // wv in [0,4)
  const int lr = lane & 15, lg = lane >> 4;
  const int krow = tid >> 2, kd = (tid & 3) * 32;  // K: row krow, 4 chunks of 8
  const int vrow = tid >> 1, vd = (tid & 1) * 32;  // V: row vrow, 4 chunks of 8
  const unsigned short* Kbase = Kb + (size_t)kh * S_LEN * HD;
  const unsigned short* Vbase = VTb + (size_t)kh * HD * S_LEN;
  const float QSC = 0.08838834764831845f * 1.44269504088896340f;  // 1/sqrt(128)*log2e

  for (int half = 0; half < 2; ++half) {
    const int qt = half ? 31 - pair : pair;  // q-tile of 64 rows
    const int q0 = qt * 64;
    const int nt = qt + 1;
    // Q load + fused RoPE + scale. Pairing: frag s (d = lg*8+s*32) with s+2 (d+64).
    bf16x8 qf[4];
    {
      const unsigned short* qp = Qb + ((size_t)h * S_LEN + q0 + wv * 16 + lr) * HD + lg * 8;
      const int pos = q0 + wv * 16 + lr;
      u16x8 qr[4], qo[4];
#pragma unroll
      for (int s = 0; s < 4; ++s) qr[s] = *(const u16x8*)(qp + s * 32);
#pragma unroll
      for (int s = 0; s < 2; ++s) {
        const float* cc = cs + pos * 64 + s * 32 + lg * 8;
#pragma unroll
        for (int j = 0; j < 8; ++j) {
          float x1 = bf2f(qr[s][j]), x2 = bf2f(qr[s + 2][j]);
          float cv = cc[j], sv = cc[S_LEN * 64 + j];
          qo[s][j] = f2bf((x1 * cv - x2 * sv) * QSC);
          qo[s + 2][j] = f2bf((x2 * cv + x1 * sv) * QSC);
        }
      }
#pragma unroll
      for (int s = 0; s < 4; ++s) qf[s] = __builtin_bit_cast(bf16x8, qo[s]);
    }
    f32x4 o[8];
#pragma unroll
    for (int i = 0; i < 8; ++i) o[i] = f32x4{0.f, 0.f, 0.f, 0.f};
    float mrow[4] = {-1e30f, -1e30f, -1e30f, -1e30f};
    float lrow[4] = {0.f, 0.f, 0.f, 0.f};

    // prologue: tile 0 -> regs -> buf0; tile 1 -> regs (tile 1 always exists in memory)
    u16x8 kreg[4], vreg[4];
    {
      const unsigned short* kp = Kbase + (size_t)krow * HD + kd;
      const unsigned short* vp = Vbase + (size_t)vrow * S_LEN + vd;
#pragma unroll
      for (int i = 0; i < 4; ++i) kreg[i] = *(const u16x8*)(kp + i * 8);
#pragma unroll
      for (int i = 0; i < 4; ++i) vreg[i] = *(const u16x8*)(vp + i * 8);
    }
    __syncthreads();  // prior half's LDS readers done
#pragma unroll
    for (int i = 0; i < 4; ++i) *(u16x8*)&Kl[0][krow][kd + i * 8] = kreg[i];
#pragma unroll
    for (int i = 0; i < 4; ++i) *(u16x8*)&Vt[0][vrow][vd + i * 8] = vreg[i];
    {
      const unsigned short* kp = Kbase + ((size_t)64 + krow) * HD + kd;
      const unsigned short* vp = Vbase + (size_t)vrow * S_LEN + 64 + vd;
#pragma unroll
      for (int i = 0; i < 4; ++i) kreg[i] = *(const u16x8*)(kp + i * 8);
#pragma unroll
      for (int i = 0; i < 4; ++i) vreg[i] = *(const u16x8*)(vp + i * 8);
    }
    __syncthreads();  // buf0 visible

    for (int t = 0; t < nt; ++t) {
      const int cb = t & 1;
      if (t + 1 < nt) {  // write tile t+1 (regs loaded at iter t-1 / prologue)
#pragma unroll
        for (int i = 0; i < 4; ++i) *(u16x8*)&Kl[cb ^ 1][krow][kd + i * 8] = kreg[i];
#pragma unroll
        for (int i = 0; i < 4; ++i) *(u16x8*)&Vt[cb ^ 1][vrow][vd + i * 8] = vreg[i];
      }
      if (t + 2 < nt) {  // issue reg-loads for tile t+2 (hide under compute)
        const unsigned short* kp = Kbase + ((size_t)(t + 2) * 64 + krow) * HD + kd;
        const unsigned short* vp = Vbase + (size_t)vrow * S_LEN + (t + 2) * 64 + vd;
#pragma unroll
        for (int i = 0; i < 4; ++i) kreg[i] = *(const u16x8*)(kp + i * 8);
#pragma unroll
        for (int i = 0; i < 4; ++i) vreg[i] = *(const u16x8*)(vp + i * 8);
      }
      const int c0 = t * 64;
      {
        f32x4 sf[4];
        __builtin_amdgcn_s_setprio(1);
#pragma unroll
        for (int c = 0; c < 4; ++c) {
          f32x4 s = {0.f, 0.f, 0.f, 0.f};
#pragma unroll
          for (int ss = 0; ss < 4; ++ss) {
            bf16x8 kf = *(const bf16x8*)&Kl[cb][c * 16 + lr][ss * 32 + lg * 8];
            s = __builtin_amdgcn_mfma_f32_16x16x32_bf16(qf[ss], kf, s, 0, 0, 0);
          }
          sf[c] = s;
        }
        __builtin_amdgcn_s_setprio(0);

        if (t == qt) {  // diagonal tile
#pragma unroll
          for (int c = 0; c < 4; ++c)
#pragma unroll
            for (int j = 0; j < 4; ++j)
              if ((c0 + c * 16 + lr) > (q0 + wv * 16 + lg * 4 + j)) sf[c][j] = -1e30f;
        }
        float tmax[4] = {-1e30f, -1e30f, -1e30f, -1e30f};
#pragma unroll
        for (int c = 0; c < 4; ++c)
#pragma unroll
          for (int j = 0; j < 4; ++j) tmax[j] = fmaxf(tmax[j], sf[c][j]);
#pragma unroll
        for (int dlt = 1; dlt < 16; dlt <<= 1)
#pragma unroll
          for (int j = 0; j < 4; ++j)
            tmax[j] = fmaxf(tmax[j], __shfl_xor(tmax[j], dlt, 64));

        // T13 defer-max: only rescale when max grows materially
        bool need = (tmax[0] > mrow[0] + 8.f) || (tmax[1] > mrow[1] + 8.f) ||
                    (tmax[2] > mrow[2] + 8.f) || (tmax[3] > mrow[3] + 8.f);
        if (__any(need)) {
          float alpha[4];
#pragma unroll
          for (int j = 0; j < 4; ++j) {
            float mn = fmaxf(mrow[j], tmax[j]);
            alpha[j] = exp2f(mrow[j] - mn);
            mrow[j] = mn;
          }
#pragma unroll
          for (int f = 0; f < 8; ++f)
#pragma unroll
            for (int j = 0; j < 4; ++j) o[f][j] *= alpha[j];
#pragma unroll
          for (int j = 0; j < 4; ++j) lrow[j] *= alpha[j];
        }
        float tsum[4] = {0.f, 0.f, 0.f, 0.f};
#pragma unroll
        for (int c = 0; c < 4; ++c)
#pragma unroll
          for (int j = 0; j < 4; ++j) {
            float pv = exp2f(sf[c][j] - mrow[j]);
            tsum[j] += pv;
            Pl[wv][lg * 4 + j][(c * 16 + lr) ^ ((lg & 2) << 2)] = f2bf(pv);
          }
#pragma unroll
        for (int dlt = 1; dlt < 16; dlt <<= 1)
#pragma unroll
          for (int j = 0; j < 4; ++j) tsum[j] += __shfl_xor(tsum[j], dlt, 64);
#pragma unroll
        for (int j = 0; j < 4; ++j) lrow[j] += tsum[j];

        // PV
        __builtin_amdgcn_s_setprio(1);
#pragma unroll
        for (int ks = 0; ks < 2; ++ks) {
          bf16x8 pa = *(const bf16x8*)&Pl[wv][lr][(ks * 32 + lg * 8) ^ (lr & 8)];
#pragma unroll
          for (int df = 0; df < 8; ++df) {
            bf16x8 vb = *(const bf16x8*)&Vt[cb][df * 16 + lr][ks * 32 + lg * 8];
            o[df] = __builtin_amdgcn_mfma_f32_16x16x32_bf16(pa, vb, o[df], 0, 0, 0);
          }
        }
        __builtin_amdgcn_s_setprio(0);
      }

      __syncthreads();  // reads of buf[cb] done + writes of buf[cb^1] drained
    }

#pragma unroll
    for (int j = 0; j < 4; ++j) {
      float inv = 1.0f / lrow[j];
      int row = q0 + wv * 16 + lg * 4 + j;
#pragma unroll
      for (int df = 0; df < 8; ++df)
        Ob[(size_t)row * (NH * HD) + h * HD + df * 16 + lr] = f2bf(o[df][j] * inv);
    }
  }
}

// ---------------- launch ----------------
extern "C" void kernel_launch(void* const* d_in, const int* in_sizes, int n_in,
                              void* d_out, int out_size, void* d_ws, size_t ws_size,
                              hipStream_t stream) {
  const float* hidden = (const float*)d_in[0];
  const float* wq = (const float*)d_in[1];
  const float* bq = (const float*)d_in[2];
  const float* wk = (const float*)d_in[3];
  const float* bk = (const float*)d_in[4];
  const float* wv = (const float*)d_in[5];
  const float* bv = (const float*)d_in[6];
  const float* wo = (const float*)d_in[7];
  float* out = (float*)d_out;

  char* p = (char*)d_ws;
  float* cs = (float*)p;                      p += (size_t)1 << 20;
  unsigned short* hb = (unsigned short*)p;    p += (size_t)16 << 20;
  unsigned short* Qb = (unsigned short*)p;    p += (size_t)16 << 20;
  unsigned short* Kbuf = (unsigned short*)p;  p += (size_t)4 << 20;
  unsigned short* VTb = (unsigned short*)p;   p += (size_t)4 << 20;
  unsigned short* attno = (unsigned short*)p; p += (size_t)16 << 20;
  unsigned short* wbuf = (unsigned short*)p;  p += (size_t)6144 * HID * 2;  // 50.3 MB qkv weights
  unsigned short* wo_sep = (unsigned short*)p;                               // +33.5 MB if ws allows

  const size_t NEED = ((size_t)57 << 20) + (size_t)6144 * HID * 2 + (size_t)HID * HID * 2;
  const bool fits = ws_size >= NEED;  // confirmed true on this harness (R12-R16 ran this path)

  if (fits) {
    hipLaunchKernelGGL(prep_all, dim3(25088), dim3(256), 0, stream,
                       hidden, wq, wk, wv, wo, hb, wbuf, wo_sep, cs);
  } else {
    hipLaunchKernelGGL(prep_all, dim3(25088), dim3(256), 0, stream,
                       hidden, wq, wk, wv, (const float*)nullptr, hb, wbuf,
                       (unsigned short*)nullptr, cs);
  }
  hipLaunchKernelGGL((gemm_nt<1>), dim3(16, 48), dim3(256), 0, stream,
                     hb, wbuf, bq, bk, bv, Qb, Kbuf, VTb);
  hipLaunchKernelGGL(rope_apply_k, dim3(4096), dim3(256), 0, stream, Kbuf, cs);
  unsigned short* wo_bf = wo_sep;
  if (!fits) {
    wo_bf = wbuf;  // qkv weights dead after QKV GEMM -> reuse
    hipLaunchKernelGGL(f2bf_kernel, dim3(8192), dim3(256), 0, stream, wo, wbuf, HID * HID / 8);
  }
  hipLaunchKernelGGL(attn_fwd, dim3(16, 32), dim3(256), 0, stream, Qb, Kbuf, VTb, cs, attno);
  hipLaunchKernelGGL(gemm_op8, dim3(8, 32), dim3(512), 0, stream, attno, wo_bf, out);
}

// Round 18
// 320.846 us; speedup vs baseline: 1.0170x; 1.0170x over previous
//
#include <hip/hip_runtime.h>
#include <hip/hip_bf16.h>

#define S_LEN 2048
#define HID 4096
#define NH 32
#define NKV 8
#define HD 128

typedef __attribute__((ext_vector_type(4))) float f32x4;
typedef __attribute__((ext_vector_type(8))) __bf16 bf16x8;
typedef __attribute__((ext_vector_type(8))) unsigned short u16x8;
typedef __attribute__((ext_vector_type(4))) unsigned short u16x4;

static __device__ __forceinline__ unsigned short f2bf(float x) {
  return __builtin_bit_cast(unsigned short, __float2bfloat16(x));
}
static __device__ __forceinline__ float bf2f(unsigned short u) {
  return __builtin_bit_cast(float, (unsigned int)u << 16);
}
static __device__ __forceinline__ void gld16(const unsigned short* g, unsigned short* l) {
  __builtin_amdgcn_global_load_lds(
      (const __attribute__((address_space(1))) unsigned int*)g,
      (__attribute__((address_space(3))) unsigned int*)l, 16, 0, 0);
}
static __device__ __forceinline__ void cvt8(const float* src, size_t off8, unsigned short* dst) {
  f32x4 a = ((const f32x4*)src)[off8 * 2];
  f32x4 b = ((const f32x4*)src)[off8 * 2 + 1];
  u16x8 w;
#pragma unroll
  for (int j = 0; j < 4; ++j) {
    w[j] = f2bf(a[j]);
    w[4 + j] = f2bf(b[j]);
  }
  ((u16x8*)dst)[off8] = w;
}

// ---------------- fp32 -> bf16 bulk convert (fallback path for wo) ----------------
__global__ void f2bf_kernel(const float* __restrict__ in, unsigned short* __restrict__ out, int n8) {
  int i = blockIdx.x * 256 + threadIdx.x;
  if (i >= n8) return;
  cvt8(in, (size_t)i, out);
}

// ---------------- prep: hidden + qkv weights + wo + rope table, ONE launch ----------------
__global__ void prep_all(const float* __restrict__ hidden, const float* __restrict__ wq,
                         const float* __restrict__ wk, const float* __restrict__ wv,
                         const float* __restrict__ woSrc,
                         unsigned short* __restrict__ hb, unsigned short* __restrict__ wbuf,
                         unsigned short* __restrict__ woDst, float* __restrict__ cs) {
  int i = blockIdx.x * 256 + threadIdx.x;
  if (i < 1048576) {
    cvt8(hidden, (size_t)i, hb);
  } else if (i < 4194304) {
    int j = i - 1048576;
    const float* src;
    size_t off;
    if (j < 2097152) { src = wq; off = j; }
    else if (j < 2621440) { src = wk; off = j - 2097152; }
    else { src = wv; off = j - 2621440; }
    f32x4 a = ((const f32x4*)src)[off * 2];
    f32x4 b = ((const f32x4*)src)[off * 2 + 1];
    u16x8 w;
#pragma unroll
    for (int jj = 0; jj < 4; ++jj) {
      w[jj] = f2bf(a[jj]);
      w[4 + jj] = f2bf(b[jj]);
    }
    ((u16x8*)wbuf)[(size_t)j] = w;
  } else if (i < 6291456) {
    if (woDst) cvt8(woSrc, (size_t)(i - 4194304), woDst);
  } else {
    int idx = i - 6291456;
    if (idx < S_LEN * 64) {
      int d = idx & 63;
      int p = idx >> 6;
      float invf = exp2f(-(float)d * (19.9315685693241741f / 64.0f));  // theta^-d/64
      float ang = (float)p * invf;
      cs[idx] = cosf(ang);
      cs[S_LEN * 64 + idx] = sinf(ang);
    }
  }
}

// ---------------- RoPE apply, K only (in-place, bf16 [head][S][128]) ----------------
__global__ void rope_apply_k(unsigned short* __restrict__ buf, const float* __restrict__ cs) {
  int idx = blockIdx.x * 256 + threadIdx.x;
  if (idx >= NKV * S_LEN * 64) return;
  int d = idx & 63;
  int hp = idx >> 6;
  int pos = hp & (S_LEN - 1);
  size_t base = (size_t)hp * HD;
  float c = cs[pos * 64 + d];
  float s = cs[S_LEN * 64 + pos * 64 + d];
  float x1 = bf2f(buf[base + d]);
  float x2 = bf2f(buf[base + 64 + d]);
  buf[base + d] = f2bf(x1 * c - x2 * s);
  buf[base + 64 + d] = f2bf(x2 * c + x1 * s);
}

// ---------------- QKV GEMM (EXACT round-2/R11 m97 structure, 852 TF measured) ----------------
// 128x128 tile, BK=32, single LDS buffer, global_load_lds(16B), 2 barriers/K-step.
// Q written WITHOUT rope (attn applies it on load).
template <int MODE>
__global__ __launch_bounds__(256) void gemm_nt(
    const unsigned short* __restrict__ A, const unsigned short* __restrict__ W,
    const float* __restrict__ bq, const float* __restrict__ bk, const float* __restrict__ bv,
    unsigned short* __restrict__ Qb, unsigned short* __restrict__ Kb,
    unsigned short* __restrict__ VTb) {
  __shared__ unsigned short As[4096];  // [128 rows][32] linear
  __shared__ unsigned short Bs[4096];
  int lin = blockIdx.x + 16 * blockIdx.y;
  int cpx = (16 * gridDim.y) >> 3;
  int swz = (lin & 7) * cpx + (lin >> 3);
  const int m0 = (swz & 15) * 128;
  const int n0 = (swz >> 4) * 128;
  const int tid = threadIdx.x, lane = tid & 63, wv = tid >> 6;
  const int wr = wv >> 1, wc = wv & 1;
  const int lr = lane & 15, lg = lane >> 4;
  const int srow = lane >> 2, skk = (lane & 3) * 8;

  const unsigned short* Ag0 = A + (size_t)(m0 + wv * 32 + srow) * HID + skk;
  const unsigned short* Ag1 = Ag0 + (size_t)16 * HID;
  const unsigned short* Wg0 = W + (size_t)(n0 + wv * 32 + srow) * HID + skk;
  const unsigned short* Wg1 = Wg0 + (size_t)16 * HID;
  unsigned short* Al0 = As + wv * 1024;  // wave-uniform LDS slice bases
  unsigned short* Al1 = As + wv * 1024 + 512;
  unsigned short* Bl0 = Bs + wv * 1024;
  unsigned short* Bl1 = Bs + wv * 1024 + 512;

  f32x4 acc[4][4] = {};

  for (int kt = 0; kt < HID / 32; ++kt) {
    const int ko = kt * 32;
    gld16(Ag0 + ko, Al0);
    gld16(Ag1 + ko, Al1);
    gld16(Wg0 + ko, Bl0);
    gld16(Wg1 + ko, Bl1);
    __syncthreads();  // drains vmcnt -> tile visible
    bf16x8 af[4], bfr[4];
#pragma unroll
    for (int i = 0; i < 4; ++i)
      af[i] = *(const bf16x8*)&As[(wr * 64 + i * 16 + lr) * 32 + lg * 8];
#pragma unroll
    for (int i = 0; i < 4; ++i)
      bfr[i] = *(const bf16x8*)&Bs[(wc * 64 + i * 16 + lr) * 32 + lg * 8];
#pragma unroll
    for (int mi = 0; mi < 4; ++mi)
#pragma unroll
      for (int ni = 0; ni < 4; ++ni)
        acc[mi][ni] = __builtin_amdgcn_mfma_f32_16x16x32_bf16(af[mi], bfr[ni], acc[mi][ni], 0, 0, 0);
    __syncthreads();  // reads done -> next stage may overwrite
  }

  {
    unsigned short* obuf;
    const float* bptr;
    int cbase;
    bool transp = false;
    if (n0 < 4096) { obuf = Qb; bptr = bq; cbase = n0; }
    else if (n0 < 5120) { obuf = Kb; bptr = bk; cbase = n0 - 4096; }
    else { obuf = VTb; bptr = bv; cbase = n0 - 5120; transp = true; }
#pragma unroll
    for (int ni = 0; ni < 4; ++ni) {
      int c = cbase + wc * 64 + ni * 16 + lr;
      float bb = bptr[c];
      if (!transp) {
        int head = c >> 7, d = c & 127;
#pragma unroll
        for (int mi = 0; mi < 4; ++mi) {
          int row = m0 + wr * 64 + mi * 16 + lg * 4;
#pragma unroll
          for (int j = 0; j < 4; ++j)
            obuf[((size_t)head * S_LEN + row + j) * HD + d] = f2bf(acc[mi][ni][j] + bb);
        }
      } else {
#pragma unroll
        for (int mi = 0; mi < 4; ++mi) {
          int row = m0 + wr * 64 + mi * 16 + lg * 4;
          u16x4 pk;
#pragma unroll
          for (int j = 0; j < 4; ++j) pk[j] = f2bf(acc[mi][ni][j] + bb);
          *(u16x4*)&VTb[(size_t)c * S_LEN + row] = pk;
        }
      }
    }
  }
}

// ---------------- Out-projection: phase rhythm + T2 swizzle (unchanged from R11-R16) ----------------
__global__ __launch_bounds__(512) void gemm_op8(const unsigned short* __restrict__ A,
                                                const unsigned short* __restrict__ W,
                                                float* __restrict__ Cout) {
  __shared__ __align__(16) unsigned short Asl[3][256 * 64];  // 96 KB
  __shared__ __align__(16) unsigned short Bsl[3][128 * 64];  // 48 KB
  int lin = blockIdx.x + 8 * blockIdx.y;
  int swz = (lin & 7) * 32 + (lin >> 3);  // XCD-chunked
  const int m0 = (swz & 7) * 256;
  const int n0 = (swz >> 3) * 128;
  const int tid = threadIdx.x, lane = tid & 63, wv = tid >> 6;
  const int wr = wv >> 1, wc = wv & 1;  // 4M x 2N waves, per-wave 64x64
  const int lr = lane & 15, lg = lane >> 4;

  const int sslot = (tid & 7) ^ ((tid >> 3) & 7);
  const unsigned short* Ag = A + (size_t)(m0 + (tid >> 3)) * HID + sslot * 8;
  const unsigned short* Wg = W + (size_t)(n0 + (tid >> 3)) * HID + sslot * 8;

  f32x4 acc[4][4] = {};

#define STAGE_A3(buf, kt)                                                     \
  {                                                                           \
    const int ko_ = (kt)*64;                                                  \
    gld16(Ag + ko_, &Asl[buf][wv * 512]);                                     \
    gld16(Ag + ko_ + (size_t)64 * HID, &Asl[buf][4096 + wv * 512]);           \
    gld16(Ag + ko_ + (size_t)128 * HID, &Asl[buf][8192 + wv * 512]);          \
  }
#define STAGE_B3(buf, kt)                                                     \
  {                                                                           \
    const int ko_ = (kt)*64;                                                  \
    gld16(Ag + ko_ + (size_t)192 * HID, &Asl[buf][12288 + wv * 512]);         \
    gld16(Wg + ko_, &Bsl[buf][wv * 512]);                                     \
    gld16(Wg + ko_ + (size_t)64 * HID, &Bsl[buf][4096 + wv * 512]);           \
  }

  STAGE_A3(0, 0); STAGE_B3(0, 0);
  STAGE_A3(1, 1); STAGE_B3(1, 1);
  asm volatile("s_waitcnt vmcnt(6)" ::: "memory");
  __builtin_amdgcn_s_barrier();

  const int NT = HID / 64;  // 64
#pragma unroll 1
  for (int kt = 0; kt < NT; ++kt) {
    const int cur = kt % 3;
    const int nxt = (kt + 2) % 3;
    bf16x8 af[4], bfr[4];
    // ---- phase 0
#pragma unroll
    for (int i = 0; i < 4; ++i)
      af[i] = *(const bf16x8*)&Asl[cur][(wr * 64 + i * 16 + lr) * 64 + ((lg ^ (lr & 7)) * 8)];
#pragma unroll
    for (int i = 0; i < 4; ++i)
      bfr[i] = *(const bf16x8*)&Bsl[cur][(wc * 64 + i * 16 + lr) * 64 + ((lg ^ (lr & 7)) * 8)];
    if (kt + 2 < NT) STAGE_A3(nxt, kt + 2);
    __builtin_amdgcn_s_barrier();
    asm volatile("s_waitcnt lgkmcnt(0)" ::: "memory");
    __builtin_amdgcn_s_setprio(1);
#pragma unroll
    for (int mi = 0; mi < 4; ++mi)
#pragma unroll
      for (int ni = 0; ni < 4; ++ni)
        acc[mi][ni] = __builtin_amdgcn_mfma_f32_16x16x32_bf16(af[mi], bfr[ni], acc[mi][ni], 0, 0, 0);
    __builtin_amdgcn_s_setprio(0);
    __builtin_amdgcn_s_barrier();
    // ---- phase 1
#pragma unroll
    for (int i = 0; i < 4; ++i)
      af[i] = *(const bf16x8*)&Asl[cur][(wr * 64 + i * 16 + lr) * 64 + (((4 + lg) ^ (lr & 7)) * 8)];
#pragma unroll
    for (int i = 0; i < 4; ++i)
      bfr[i] = *(const bf16x8*)&Bsl[cur][(wc * 64 + i * 16 + lr) * 64 + (((4 + lg) ^ (lr & 7)) * 8)];
    if (kt + 2 < NT) {
      STAGE_B3(nxt, kt + 2);
      asm volatile("s_waitcnt vmcnt(6)" ::: "memory");
    } else if (kt + 1 < NT) {
      asm volatile("s_waitcnt vmcnt(0)" ::: "memory");
    }
    __builtin_amdgcn_s_barrier();
    asm volatile("s_waitcnt lgkmcnt(0)" ::: "memory");
    __builtin_amdgcn_s_setprio(1);
#pragma unroll
    for (int mi = 0; mi < 4; ++mi)
#pragma unroll
      for (int ni = 0; ni < 4; ++ni)
        acc[mi][ni] = __builtin_amdgcn_mfma_f32_16x16x32_bf16(af[mi], bfr[ni], acc[mi][ni], 0, 0, 0);
    __builtin_amdgcn_s_setprio(0);
    __builtin_amdgcn_s_barrier();
  }
#undef STAGE_A3
#undef STAGE_B3

#pragma unroll
  for (int mi = 0; mi < 4; ++mi) {
    int row = m0 + wr * 64 + mi * 16 + lg * 4;
#pragma unroll
    for (int ni = 0; ni < 4; ++ni) {
      int col = n0 + wc * 64 + ni * 16 + lr;
#pragma unroll
      for (int j = 0; j < 4; ++j)
        Cout[(size_t)(row + j) * HID + col] = acc[mi][ni][j];
    }
  }
}

// ---------------- Flash attention (EXACT R16 form — measured 53 us) ----------------
// QBLK=128, 8 waves, grid (8,32) = 256 blocks = 1/CU. Double-buffered K/V LDS,
// ONE barrier per tile. R17's QBLK=64 2-blocks/CU variant REGRESSED (+5 us):
// 79KB static LDS rounds past the 80KB half-CU boundary -> still 1 block/CU with
// double the K/V traffic. Do not reintroduce.
__global__ __launch_bounds__(512) void attn_fwd(const unsigned short* __restrict__ Qb,
                                                const unsigned short* __restrict__ Kb,
                                                const unsigned short* __restrict__ VTb,
                                                const float* __restrict__ cs,
                                                unsigned short* __restrict__ Ob) {
  __shared__ unsigned short Kl[2][64][136];
  __shared__ unsigned short Vt[2][128][72];
  __shared__ unsigned short Pl[8][16][72];
  int lin = blockIdx.x + 8 * blockIdx.y;
  int swz = (lin & 7) * 32 + (lin >> 3);  // each XCD owns 4 q-heads = 1 kv-head
  const int pair = swz & 7;
  const int h = swz >> 3;
  const int kh = h >> 2;
  const int tid = threadIdx.x, lane = tid & 63, wv = tid >> 6;
  const int lr = lane & 15, lg = lane >> 4;
  const int krow = tid >> 4, koff = (tid & 15) * 8;   // K rows krow, krow+32
  const int vrow = tid >> 3, voff = (tid & 7) * 8;    // V rows vrow, vrow+64
  const unsigned short* Kbase = Kb + (size_t)kh * S_LEN * HD;
  const unsigned short* Vbase = VTb + (size_t)kh * HD * S_LEN;
  const float QSC = 0.08838834764831845f * 1.44269504088896340f;  // 1/sqrt(128)*log2e

  for (int half = 0; half < 2; ++half) {
    const int qt = half ? 15 - pair : pair;
    const int q0 = qt * 128;
    const int nt = 2 * qt + 2;  // always >= 2
    // Q load + fused RoPE + scale. Pairing: frag s (d = lg*8+s*32) with s+2 (d+64).
    bf16x8 qf[4];
    {
      const unsigned short* qp = Qb + ((size_t)h * S_LEN + q0 + wv * 16 + lr) * HD + lg * 8;
      const int pos = q0 + wv * 16 + lr;
      u16x8 qr[4], qo[4];
#pragma unroll
      for (int s = 0; s < 4; ++s) qr[s] = *(const u16x8*)(qp + s * 32);
#pragma unroll
      for (int s = 0; s < 2; ++s) {
        const float* cc = cs + pos * 64 + s * 32 + lg * 8;
#pragma unroll
        for (int j = 0; j < 8; ++j) {
          float x1 = bf2f(qr[s][j]), x2 = bf2f(qr[s + 2][j]);
          float cv = cc[j], sv = cc[S_LEN * 64 + j];
          qo[s][j] = f2bf((x1 * cv - x2 * sv) * QSC);
          qo[s + 2][j] = f2bf((x2 * cv + x1 * sv) * QSC);
        }
      }
#pragma unroll
      for (int s = 0; s < 4; ++s) qf[s] = __builtin_bit_cast(bf16x8, qo[s]);
    }
    f32x4 o[8];
#pragma unroll
    for (int i = 0; i < 8; ++i) o[i] = f32x4{0.f, 0.f, 0.f, 0.f};
    float mrow[4] = {-1e30f, -1e30f, -1e30f, -1e30f};
    float lrow[4] = {0.f, 0.f, 0.f, 0.f};

    // prologue: tile 0 -> regs -> buf0; tile 1 -> regs
    u16x8 kreg[2], vreg[2];
    {
      const unsigned short* kp = Kbase + (size_t)krow * HD + koff;
      const unsigned short* vp = Vbase + (size_t)vrow * S_LEN + voff;
      kreg[0] = *(const u16x8*)kp;
      kreg[1] = *(const u16x8*)(kp + (size_t)32 * HD);
      vreg[0] = *(const u16x8*)vp;
      vreg[1] = *(const u16x8*)(vp + (size_t)64 * S_LEN);
    }
    __syncthreads();  // prior half's LDS readers done
    *(u16x8*)&Kl[0][krow][koff] = kreg[0];
    *(u16x8*)&Kl[0][krow + 32][koff] = kreg[1];
    *(u16x8*)&Vt[0][vrow][voff] = vreg[0];
    *(u16x8*)&Vt[0][vrow + 64][voff] = vreg[1];
    {
      const unsigned short* kp = Kbase + ((size_t)64 + krow) * HD + koff;
      const unsigned short* vp = Vbase + (size_t)vrow * S_LEN + 64 + voff;
      kreg[0] = *(const u16x8*)kp;
      kreg[1] = *(const u16x8*)(kp + (size_t)32 * HD);
      vreg[0] = *(const u16x8*)vp;
      vreg[1] = *(const u16x8*)(vp + (size_t)64 * S_LEN);
    }
    __syncthreads();  // buf0 visible

    for (int t = 0; t < nt; ++t) {
      const int cb = t & 1;
      if (t + 1 < nt) {  // write tile t+1 (regs loaded at iter t-1 / prologue)
        *(u16x8*)&Kl[cb ^ 1][krow][koff] = kreg[0];
        *(u16x8*)&Kl[cb ^ 1][krow + 32][koff] = kreg[1];
        *(u16x8*)&Vt[cb ^ 1][vrow][voff] = vreg[0];
        *(u16x8*)&Vt[cb ^ 1][vrow + 64][voff] = vreg[1];
      }
      if (t + 2 < nt) {  // issue reg-loads for tile t+2 (hide under compute)
        const unsigned short* kp = Kbase + ((size_t)(t + 2) * 64 + krow) * HD + koff;
        const unsigned short* vp = Vbase + (size_t)vrow * S_LEN + (t + 2) * 64 + voff;
        kreg[0] = *(const u16x8*)kp;
        kreg[1] = *(const u16x8*)(kp + (size_t)32 * HD);
        vreg[0] = *(const u16x8*)vp;
        vreg[1] = *(const u16x8*)(vp + (size_t)64 * S_LEN);
      }
      const int c0 = t * 64;
      const bool active = (c0 <= q0 + wv * 16 + 15);  // wave-uniform: skip fully-masked
      if (active) {
        f32x4 sf[4];
        __builtin_amdgcn_s_setprio(1);
#pragma unroll
        for (int c = 0; c < 4; ++c) {
          f32x4 s = {0.f, 0.f, 0.f, 0.f};
#pragma unroll
          for (int ss = 0; ss < 4; ++ss) {
            bf16x8 kf = *(const bf16x8*)&Kl[cb][c * 16 + lr][ss * 32 + lg * 8];
            s = __builtin_amdgcn_mfma_f32_16x16x32_bf16(qf[ss], kf, s, 0, 0, 0);
          }
          sf[c] = s;
        }
        __builtin_amdgcn_s_setprio(0);

        if (t >= 2 * qt) {  // diagonal tiles only
#pragma unroll
          for (int c = 0; c < 4; ++c)
#pragma unroll
            for (int j = 0; j < 4; ++j)
              if ((c0 + c * 16 + lr) > (q0 + wv * 16 + lg * 4 + j)) sf[c][j] = -1e30f;
        }
        float tmax[4] = {-1e30f, -1e30f, -1e30f, -1e30f};
#pragma unroll
        for (int c = 0; c < 4; ++c)
#pragma unroll
          for (int j = 0; j < 4; ++j) tmax[j] = fmaxf(tmax[j], sf[c][j]);
#pragma unroll
        for (int dlt = 1; dlt < 16; dlt <<= 1)
#pragma unroll
          for (int j = 0; j < 4; ++j)
            tmax[j] = fmaxf(tmax[j], __shfl_xor(tmax[j], dlt, 64));

        // T13 defer-max: only rescale when max grows materially
        bool need = (tmax[0] > mrow[0] + 8.f) || (tmax[1] > mrow[1] + 8.f) ||
                    (tmax[2] > mrow[2] + 8.f) || (tmax[3] > mrow[3] + 8.f);
        if (__any(need)) {
          float alpha[4];
#pragma unroll
          for (int j = 0; j < 4; ++j) {
            float mn = fmaxf(mrow[j], tmax[j]);
            alpha[j] = exp2f(mrow[j] - mn);
            mrow[j] = mn;
          }
#pragma unroll
          for (int f = 0; f < 8; ++f)
#pragma unroll
            for (int j = 0; j < 4; ++j) o[f][j] *= alpha[j];
#pragma unroll
          for (int j = 0; j < 4; ++j) lrow[j] *= alpha[j];
        }
        float tsum[4] = {0.f, 0.f, 0.f, 0.f};
#pragma unroll
        for (int c = 0; c < 4; ++c)
#pragma unroll
          for (int j = 0; j < 4; ++j) {
            float pv = exp2f(sf[c][j] - mrow[j]);
            tsum[j] += pv;
            Pl[wv][lg * 4 + j][(c * 16 + lr) ^ ((lg & 2) << 2)] = f2bf(pv);
          }
#pragma unroll
        for (int dlt = 1; dlt < 16; dlt <<= 1)
#pragma unroll
          for (int j = 0; j < 4; ++j) tsum[j] += __shfl_xor(tsum[j], dlt, 64);
#pragma unroll
        for (int j = 0; j < 4; ++j) lrow[j] += tsum[j];

        // PV
        __builtin_amdgcn_s_setprio(1);
#pragma unroll
        for (int ks = 0; ks < 2; ++ks) {
          bf16x8 pa = *(const bf16x8*)&Pl[wv][lr][(ks * 32 + lg * 8) ^ (lr & 8)];
#pragma unroll
          for (int df = 0; df < 8; ++df) {
            bf16x8 vb = *(const bf16x8*)&Vt[cb][df * 16 + lr][ks * 32 + lg * 8];
            o[df] = __builtin_amdgcn_mfma_f32_16x16x32_bf16(pa, vb, o[df], 0, 0, 0);
          }
        }
        __builtin_amdgcn_s_setprio(0);
      }

      __syncthreads();  // reads of buf[cb] done + writes of buf[cb^1] drained
    }

#pragma unroll
    for (int j = 0; j < 4; ++j) {
      float inv = 1.0f / lrow[j];
      int row = q0 + wv * 16 + lg * 4 + j;
#pragma unroll
      for (int df = 0; df < 8; ++df)
        Ob[(size_t)row * (NH * HD) + h * HD + df * 16 + lr] = f2bf(o[df][j] * inv);
    }
  }
}

// ---------------- launch ----------------
extern "C" void kernel_launch(void* const* d_in, const int* in_sizes, int n_in,
                              void* d_out, int out_size, void* d_ws, size_t ws_size,
                              hipStream_t stream) {
  const float* hidden = (const float*)d_in[0];
  const float* wq = (const float*)d_in[1];
  const float* bq = (const float*)d_in[2];
  const float* wk = (const float*)d_in[3];
  const float* bk = (const float*)d_in[4];
  const float* wv = (const float*)d_in[5];
  const float* bv = (const float*)d_in[6];
  const float* wo = (const float*)d_in[7];
  float* out = (float*)d_out;

  char* p = (char*)d_ws;
  float* cs = (float*)p;                      p += (size_t)1 << 20;
  unsigned short* hb = (unsigned short*)p;    p += (size_t)16 << 20;
  unsigned short* Qb = (unsigned short*)p;    p += (size_t)16 << 20;
  unsigned short* Kbuf = (unsigned short*)p;  p += (size_t)4 << 20;
  unsigned short* VTb = (unsigned short*)p;   p += (size_t)4 << 20;
  unsigned short* attno = (unsigned short*)p; p += (size_t)16 << 20;
  unsigned short* wbuf = (unsigned short*)p;  p += (size_t)6144 * HID * 2;  // 50.3 MB qkv weights
  unsigned short* wo_sep = (unsigned short*)p;                               // +33.5 MB if ws allows

  const size_t NEED = ((size_t)57 << 20) + (size_t)6144 * HID * 2 + (size_t)HID * HID * 2;
  const bool fits = ws_size >= NEED;  // confirmed true on this harness (R12-R17 ran this path)

  if (fits) {
    hipLaunchKernelGGL(prep_all, dim3(25088), dim3(256), 0, stream,
                       hidden, wq, wk, wv, wo, hb, wbuf, wo_sep, cs);
  } else {
    hipLaunchKernelGGL(prep_all, dim3(25088), dim3(256), 0, stream,
                       hidden, wq, wk, wv, (const float*)nullptr, hb, wbuf,
                       (unsigned short*)nullptr, cs);
  }
  hipLaunchKernelGGL((gemm_nt<1>), dim3(16, 48), dim3(256), 0, stream,
                     hb, wbuf, bq, bk, bv, Qb, Kbuf, VTb);
  hipLaunchKernelGGL(rope_apply_k, dim3(4096), dim3(256), 0, stream, Kbuf, cs);
  unsigned short* wo_bf = wo_sep;
  if (!fits) {
    wo_bf = wbuf;  // qkv weights dead after QKV GEMM -> reuse
    hipLaunchKernelGGL(f2bf_kernel, dim3(8192), dim3(256), 0, stream, wo, wbuf, HID * HID / 8);
  }
  hipLaunchKernelGGL(attn_fwd, dim3(8, 32), dim3(512), 0, stream, Qb, Kbuf, VTb, cs, attno);
  hipLaunchKernelGGL(gemm_op8, dim3(8, 32), dim3(512), 0, stream, attno, wo_bf, out);
}